// Round 2
// 181.805 us; speedup vs baseline: 1.2147x; 1.2147x over previous
//
#include <hip/hip_runtime.h>

typedef unsigned short u16;
typedef unsigned int u32;
typedef __attribute__((ext_vector_type(4))) float f32x4;
typedef __attribute__((ext_vector_type(16))) float f32x16;
typedef __attribute__((ext_vector_type(8))) short bf16x8;

constexpr int B_ = 2, T_ = 4096, S_ = 4096, G_ = 64, D_ = 1024, H_ = 16, W_ = 512, CHUNK_ = 256;
constexpr int NC_ = T_ / CHUNK_;   // 16 chunks
constexpr int NT_ = (G_ + W_) / 32; // 18 key tiles of 32 (2 global + 16 window)

__device__ __forceinline__ u16 f2bf(float x) {
  u32 u = __builtin_bit_cast(u32, x);
  return (u16)((u + 0x7FFFu + ((u >> 16) & 1u)) >> 16);
}

// ---------------- f32 -> bf16 conversion ----------------
__global__ __launch_bounds__(256) void cvt_kernel(const float* __restrict__ s, u16* __restrict__ d, int n4) {
  int i = blockIdx.x * 256 + threadIdx.x;
  if (i >= n4) return;
  float4 v = ((const float4*)s)[i];
  uint2 o;
  o.x = (u32)f2bf(v.x) | ((u32)f2bf(v.y) << 16);
  o.y = (u32)f2bf(v.z) | ((u32)f2bf(v.w) << 16);
  ((uint2*)d)[i] = o;
}

__global__ __launch_bounds__(256) void cvt6_kernel(const float* s0, const float* s1, const float* s2,
                                                   const float* s3, const float* s4, const float* s5,
                                                   u16* __restrict__ dst) {
  const float* ss[6] = {s0, s1, s2, s3, s4, s5};
  int t = blockIdx.y;
  const float4* sp = (const float4*)ss[t];
  u16* d = dst + (size_t)t * (D_ * D_);
  int i = blockIdx.x * 256 + threadIdx.x;  // grid sized exactly: 262144 float4 per weight
  float4 v = sp[i];
  uint2 o;
  o.x = (u32)f2bf(v.x) | ((u32)f2bf(v.y) << 16);
  o.y = (u32)f2bf(v.z) | ((u32)f2bf(v.w) << 16);
  ((uint2*)d)[i] = o;
}

// ---------------- bf16 GEMM: C[M,N] = A[M,K] * Bt[N,K]^T + bias ----------------
// MODE 0: store bf16; MODE 1: store bf16 scaled by 0.125*log2(e) (q scale, exp2-domain softmax);
// MODE 2: store f32; MODE 3: bf16 dual-output (col<1024 -> out/bias, col>=1024 -> out+split-1024/bias2)
template <int MODE>
__global__ __launch_bounds__(256) void gemm_kernel(const u16* __restrict__ A, const u16* __restrict__ Bt,
                                                   const float* __restrict__ bias, const float* __restrict__ bias2,
                                                   size_t split, void* __restrict__ out) {
  __shared__ u16 As[128 * 32];
  __shared__ u16 Bs[128 * 32];
  const int tid = threadIdx.x;
  const int lane = tid & 63;
  const int wv = tid >> 6;
  const int wr = wv >> 1, wc = wv & 1;
  const int l15 = lane & 15, kg = lane >> 4;
  const int row0 = blockIdx.x * 128;
  const int col0 = blockIdx.y * 128;

  f32x4 acc[4][4];
#pragma unroll
  for (int i = 0; i < 4; i++)
#pragma unroll
    for (int j = 0; j < 4; j++)
#pragma unroll
      for (int r = 0; r < 4; r++) acc[i][j][r] = 0.f;

  const char* Abase = (const char*)A;
  const char* Bbase = (const char*)Bt;

  for (int k0 = 0; k0 < 1024; k0 += 32) {
    __syncthreads();  // previous compute done before overwriting LDS
#pragma unroll
    for (int c = 0; c < 2; c++) {
      int beta = wv * 2048 + c * 1024 + lane * 16;  // byte pos within 8KB tile
      int arow = beta >> 6;                          // row (64B per row of 32 bf16)
      int kb = beta & 63;
      const char* ga = Abase + ((size_t)(row0 + arow) * 2048 + (size_t)k0 * 2 + kb);
      __builtin_amdgcn_global_load_lds((const __attribute__((address_space(1))) void*)ga,
                                       (__attribute__((address_space(3))) void*)((char*)As + wv * 2048 + c * 1024),
                                       16, 0, 0);
      const char* gb = Bbase + ((size_t)(col0 + arow) * 2048 + (size_t)k0 * 2 + kb);
      __builtin_amdgcn_global_load_lds((const __attribute__((address_space(1))) void*)gb,
                                       (__attribute__((address_space(3))) void*)((char*)Bs + wv * 2048 + c * 1024),
                                       16, 0, 0);
    }
    __syncthreads();  // drains vmcnt for global_load_lds

    bf16x8 af[4], bfv[4];
#pragma unroll
    for (int mi = 0; mi < 4; mi++) af[mi] = *(const bf16x8*)(As + ((wr * 64 + mi * 16 + l15) * 32 + kg * 8));
#pragma unroll
    for (int ni = 0; ni < 4; ni++) bfv[ni] = *(const bf16x8*)(Bs + ((wc * 64 + ni * 16 + l15) * 32 + kg * 8));
#pragma unroll
    for (int mi = 0; mi < 4; mi++)
#pragma unroll
      for (int ni = 0; ni < 4; ni++)
        acc[mi][ni] = __builtin_amdgcn_mfma_f32_16x16x32_bf16(af[mi], bfv[ni], acc[mi][ni], 0, 0, 0);
  }

  const float* bp = bias;
  size_t obase = 0;
  if (MODE == 3 && col0 >= 1024) {
    bp = bias2 - 1024;
    obase = split - 1024;
  }
  float bv[4];
#pragma unroll
  for (int ni = 0; ni < 4; ni++) bv[ni] = bp[col0 + wc * 64 + ni * 16 + l15];
#pragma unroll
  for (int mi = 0; mi < 4; mi++) {
    int grow0 = row0 + wr * 64 + mi * 16 + kg * 4;
#pragma unroll
    for (int r = 0; r < 4; r++) {
      int grow = grow0 + r;
#pragma unroll
      for (int ni = 0; ni < 4; ni++) {
        float v = acc[mi][ni][r] + bv[ni];
        if (MODE == 1) v *= 0.18033688011112042f;  // (1/8) * log2(e)
        int gcol = col0 + wc * 64 + ni * 16 + l15;
        if (MODE == 2)
          ((float*)out)[(size_t)grow * 1024 + gcol] = v;
        else
          ((u16*)out)[obase + (size_t)grow * 1024 + gcol] = f2bf(v);
      }
    }
  }
}

// ---------------- fused attention ----------------
// grid (nC, H, B), 512 threads = 8 waves; wave w owns queries [c*256 + w*32, +32)
// Swapped-operand MFMA: S^T = mfma(K, Q) so q = lane&31 (lane-local softmax/rescale),
// PV as O^T = mfma(V^T, P^T). Scores arrive in log2 domain (q pre-scaled by 0.125*log2e).
// Pipeline: double-buffered K/Vt in LDS, ONE barrier per tile; next tile's global loads
// are issued before the barrier so their latency hides under this tile's compute.
// Cross-lane exchanges use __shfl_xor (harness-verified); permlane32_swap direction was
// the round-1 correctness bug candidate and is not used.
__global__ __launch_bounds__(512, 4) void attn_kernel(const u16* __restrict__ q_bf, const u16* __restrict__ k_bf,
                                                      const u16* __restrict__ v_bf, const u16* __restrict__ gk_bf,
                                                      const u16* __restrict__ gv_bf, u16* __restrict__ ao,
                                                      const int* __restrict__ rptr) {
  // 32KB LDS: K dbuf [0,8192) (4KB each, XOR-swizzled rows);
  // Vt dbuf [8192, 8192+2*5248): row hd at hd*80 + (hd>>3)*16 (+16B skew per 8 rows kills the
  // 8-way write conflict of the transpose scatter while keeping b128 reads conflict-free).
  // Epilogue reuses all 32KB.
  __shared__ u16 smem[16384];
  const int c = blockIdx.x, h = blockIdx.y, b = blockIdx.z;
  const int tid = threadIdx.x;
  const int lane = tid & 63, wv = tid >> 6;
  const int l31 = lane & 31, half = lane >> 5;
  const int t0 = c * CHUNK_;

  int rr = rptr[0];
  int centert = c * CHUNK_ + CHUNK_ / 2;
  int expected = (int)((float)centert / (float)rr);
  expected = min(max(expected, 0), S_ - 1);
  int ws0 = min(max(expected - W_ / 2, 0), S_ - W_);

  // Q fragments (B-operand): lane holds Q[q=l31][hd = half*8+e + 16*s], q pre-scaled by 0.125*log2e
  bf16x8 qf[4];
  {
    const u16* qrow = q_bf + ((size_t)(b * T_ + t0 + wv * 32 + l31)) * D_ + h * 64 + half * 8;
#pragma unroll
    for (int s = 0; s < 4; s++) qf[s] = *(const bf16x8*)(qrow + s * 16);
  }

  const int skey = (tid & 255) >> 3, shq = tid & 7;
  const bool isK = tid < 256;

  auto load_tile = [&](int j) -> uint4 {
    const u16* base;
    size_t row;
    if (j < 2) {
      base = isK ? gk_bf : gv_bf;
      row = (size_t)(b * G_ + j * 32 + skey);
    } else {
      base = isK ? k_bf : v_bf;
      row = (size_t)(b * S_ + ws0 + (j - 2) * 32 + skey);
    }
    return *(const uint4*)(base + row * D_ + h * 64 + shq * 8);
  };

  f32x16 oacc[2];
#pragma unroll
  for (int i = 0; i < 2; i++)
#pragma unroll
    for (int r = 0; r < 16; r++) oacc[i][r] = 0.f;
  float mrun = -1e30f, lsum = 0.f;

  uint4 stg = load_tile(0);

  for (int j = 0; j < NT_; j++) {
    const int bsel = j & 1;
    // ---- write staged tile (regs -> LDS buf[bsel]); prev compute read buf[bsel^1]: no race
    if (isK) {
      *(uint4*)((char*)smem + bsel * 4096 + ((skey * 128 + shq * 16) ^ ((skey & 7) << 4))) = stg;
    } else {
      const u16* pv = (const u16*)&stg;
      char* bp = (char*)smem + 8192 + bsel * 5248 + shq * 656 + skey * 2;  // 656 = 8*80+16 (row skew)
#pragma unroll
      for (int e = 0; e < 8; e++) *(u16*)(bp + e * 80) = pv[e];
    }
    // ---- issue next tile's global loads before the barrier (latency hides under compute)
    if (j + 1 < NT_) stg = load_tile(j + 1);
    __syncthreads();

    const int kbase = bsel * 4096;
    const int vtb = 8192 + bsel * 5248;

    // S^T = K * Q^T  (A = K tile: row=key=l31, k = half*8+e+16s)
    f32x16 sacc;
#pragma unroll
    for (int r = 0; r < 16; r++) sacc[r] = 0.f;
    __builtin_amdgcn_s_setprio(1);
#pragma unroll
    for (int s = 0; s < 4; s++) {
      int kb = kbase + ((l31 * 128 + half * 16 + s * 32) ^ ((l31 & 7) << 4));
      bf16x8 kf = *(const bf16x8*)((char*)smem + kb);
      sacc = __builtin_amdgcn_mfma_f32_32x32x16_bf16(kf, qf[s], sacc, 0, 0, 0);
    }
    __builtin_amdgcn_s_setprio(0);

    // online softmax in log2 domain; q is lane-local (col); max3-friendly reduction tree
    float t0m = fmaxf(fmaxf(sacc[0], sacc[1]), sacc[2]);
    float t1m = fmaxf(fmaxf(sacc[3], sacc[4]), sacc[5]);
    float t2m = fmaxf(fmaxf(sacc[6], sacc[7]), sacc[8]);
    float t3m = fmaxf(fmaxf(sacc[9], sacc[10]), sacc[11]);
    float t4m = fmaxf(fmaxf(sacc[12], sacc[13]), sacc[14]);
    float tmax = fmaxf(fmaxf(fmaxf(t0m, t1m), fmaxf(t2m, t3m)), fmaxf(t4m, sacc[15]));
    tmax = fmaxf(tmax, __shfl_xor(tmax, 32));
    // defer-max (T13): rescale only when the running max grew by > 8 (P bounded by 2^8)
    if (__any(tmax > mrun + 8.f)) {
      float mnew = fmaxf(mrun, tmax);
      float fac = __builtin_amdgcn_exp2f(mrun - mnew);
      mrun = mnew;
      lsum *= fac;
#pragma unroll
      for (int i = 0; i < 2; i++)
#pragma unroll
        for (int r = 0; r < 16; r++) oacc[i][r] *= fac;
    }
    float p[16];
#pragma unroll
    for (int r = 0; r < 16; r++) p[r] = __builtin_amdgcn_exp2f(sacc[r] - mrun);
    float s0s = (p[0] + p[1]) + (p[2] + p[3]);
    float s1s = (p[4] + p[5]) + (p[6] + p[7]);
    float s2s = (p[8] + p[9]) + (p[10] + p[11]);
    float s3s = (p[12] + p[13]) + (p[14] + p[15]);
    float tsum = (s0s + s1s) + (s2s + s3s);
    tsum += __shfl_xor(tsum, 32);
    lsum += tsum;

    // pack P^T into B-operand frags: cvt_pk pairs (lane-local), then shfl_xor(32)+select
    // exchanges halves (keys (r&3)+8*(r>>2)+4*half -> k=8*half+e order). Harness-verified form.
    u32 xs[8], px[8];
#pragma unroll
    for (int i = 0; i < 8; i++)
      asm("v_cvt_pk_bf16_f32 %0, %1, %2" : "=v"(xs[i]) : "v"(p[2 * i]), "v"(p[2 * i + 1]));
#pragma unroll
    for (int i = 0; i < 8; i++) px[i] = (u32)__shfl_xor((int)xs[i], 32);
    u32 Bk[2][4];
    Bk[0][0] = half ? px[2] : xs[0];
    Bk[0][1] = half ? px[3] : xs[1];
    Bk[0][2] = half ? xs[2] : px[0];
    Bk[0][3] = half ? xs[3] : px[1];
    Bk[1][0] = half ? px[6] : xs[4];
    Bk[1][1] = half ? px[7] : xs[5];
    Bk[1][2] = half ? xs[6] : px[4];
    Bk[1][3] = half ? xs[7] : px[5];

    // O^T += V^T * P^T   (A = Vt: row=hd (skewed layout), k=key; B = P^T: col=q, k=key)
    int vro = vtb + l31 * 80 + ((l31 >> 3) << 4) + half * 16;
    __builtin_amdgcn_s_setprio(1);
#pragma unroll
    for (int hdf = 0; hdf < 2; hdf++) {
#pragma unroll
      for (int ks = 0; ks < 2; ks++) {
        bf16x8 vf = *(const bf16x8*)((const char*)smem + vro + hdf * 2624 + ks * 32);  // 2624 = 32*80+64
        uint4 u4;
        u4.x = Bk[ks][0]; u4.y = Bk[ks][1]; u4.z = Bk[ks][2]; u4.w = Bk[ks][3];
        bf16x8 pb = __builtin_bit_cast(bf16x8, u4);
        oacc[hdf] = __builtin_amdgcn_mfma_f32_32x32x16_bf16(vf, pb, oacc[hdf], 0, 0, 0);
      }
    }
    __builtin_amdgcn_s_setprio(0);
  }

  // epilogue: O^T -> LDS (transpose to [q][hd], swizzled) -> coalesced global store
  __syncthreads();
  float inv = 1.f / lsum;
#pragma unroll
  for (int hdf = 0; hdf < 2; hdf++) {
#pragma unroll
    for (int a = 0; a < 4; a++) {
      float f0 = oacc[hdf][4 * a] * inv, f1 = oacc[hdf][4 * a + 1] * inv;
      float f2 = oacc[hdf][4 * a + 2] * inv, f3 = oacc[hdf][4 * a + 3] * inv;
      uint2 o;
      asm("v_cvt_pk_bf16_f32 %0, %1, %2" : "=v"(o.x) : "v"(f0), "v"(f1));
      asm("v_cvt_pk_bf16_f32 %0, %1, %2" : "=v"(o.y) : "v"(f2), "v"(f3));
      int off = wv * 4096 + l31 * 128 + ((16 * a + 8 * half + 64 * hdf) ^ ((l31 & 7) << 4));
      *(uint2*)((char*)smem + off) = o;
    }
  }
  __syncthreads();
#pragma unroll
  for (int it = 0; it < 4; it++) {
    int byteo = (tid + it * 512) * 16;
    int row = byteo >> 7;       // q within chunk, 0..255
    int colb = byteo & 127;     // hd byte offset
    uint4 vv = *(const uint4*)((const char*)smem + row * 128 + (colb ^ ((row & 7) << 4)));
    *(uint4*)(ao + ((size_t)(b * T_ + t0 + row)) * D_ + h * 64 + (colb >> 1)) = vv;
  }
}

extern "C" void kernel_launch(void* const* d_in, const int* in_sizes, int n_in,
                              void* d_out, int out_size, void* d_ws, size_t ws_size,
                              hipStream_t stream) {
  (void)in_sizes; (void)n_in; (void)out_size; (void)ws_size;
  const float* query = (const float*)d_in[0];
  const float* enc = (const float*)d_in[1];
  const float* glob = (const float*)d_in[2];
  const float* qw = (const float*)d_in[3];
  const float* qb = (const float*)d_in[4];
  const float* kw = (const float*)d_in[5];
  const float* kb = (const float*)d_in[6];
  const float* vw = (const float*)d_in[7];
  const float* vb = (const float*)d_in[8];
  const float* gkw = (const float*)d_in[9];
  const float* gkb = (const float*)d_in[10];
  const float* gvw = (const float*)d_in[11];
  const float* gvb = (const float*)d_in[12];
  const float* ow = (const float*)d_in[13];
  const float* ob = (const float*)d_in[14];
  const int* rp = (const int*)d_in[15];

  const size_t NQ = (size_t)B_ * T_ * D_;   // 8388608
  const size_t NG = (size_t)B_ * G_ * D_;   // 131072
  const size_t NW = (size_t)D_ * D_;        // 1048576

  u16* ws = (u16*)d_ws;
  u16* qx = ws;                // bf16 query
  u16* ex = qx + NQ;           // bf16 encoder_out
  u16* gx = ex + NQ;           // bf16 global_tokens
  u16* wgt = gx + NG;          // 6 weights bf16 (qw,kw,vw,gkw,gvw,ow) — contiguous!
  u16* q_bf = wgt + 6 * NW;    // projected q (pre-scaled by 0.125*log2e)
  u16* k_bf = q_bf + NQ;
  u16* v_bf = k_bf + NQ;       // contiguous after k_bf (enables fused K|V gemm)
  u16* gk_bf = v_bf + NQ;
  u16* gv_bf = gk_bf + NG;     // contiguous after gk_bf (enables fused GK|GV gemm)
  u16* ao = gv_bf + NG;        // attention output bf16 [B*T, D]

  cvt_kernel<<<8192, 256, 0, stream>>>(query, qx, (int)(NQ / 4));
  cvt_kernel<<<8192, 256, 0, stream>>>(enc, ex, (int)(NQ / 4));
  cvt_kernel<<<128, 256, 0, stream>>>(glob, gx, (int)(NG / 4));
  cvt6_kernel<<<dim3(1024, 6), 256, 0, stream>>>(qw, kw, vw, gkw, gvw, ow, wgt);

  gemm_kernel<1><<<dim3(64, 8), 256, 0, stream>>>(qx, wgt + 0 * NW, qb, qb, 0, q_bf);
  // fused K|V projection: Bt rows [0,2048) span kw then vw; outputs k_bf then v_bf
  gemm_kernel<3><<<dim3(64, 16), 256, 0, stream>>>(ex, wgt + 1 * NW, kb, vb, NQ, k_bf);
  // fused GK|GV projection
  gemm_kernel<3><<<dim3(1, 16), 256, 0, stream>>>(gx, wgt + 3 * NW, gkb, gvb, NG, gk_bf);

  attn_kernel<<<dim3(NC_, H_, B_), 512, 0, stream>>>(q_bf, k_bf, v_bf, gk_bf, gv_bf, ao, rp);

  gemm_kernel<2><<<dim3(64, 8), 256, 0, stream>>>(ao, wgt + 5 * NW, ob, ob, 0, d_out);
}

// Round 3
// 171.159 us; speedup vs baseline: 1.2903x; 1.0622x over previous
//
#include <hip/hip_runtime.h>

typedef unsigned short u16;
typedef unsigned int u32;
typedef __attribute__((ext_vector_type(4))) float f32x4;
typedef __attribute__((ext_vector_type(16))) float f32x16;
typedef __attribute__((ext_vector_type(8))) short bf16x8;

constexpr int B_ = 2, T_ = 4096, S_ = 4096, G_ = 64, D_ = 1024, H_ = 16, W_ = 512, CHUNK_ = 256;
constexpr int NC_ = T_ / CHUNK_;   // 16 chunks
constexpr int NT_ = (G_ + W_) / 32; // 18 key tiles of 32 (2 global + 16 window)

__device__ __forceinline__ u16 f2bf(float x) {
  u32 u = __builtin_bit_cast(u32, x);
  return (u16)((u + 0x7FFFu + ((u >> 16) & 1u)) >> 16);
}

// ---------------- fused f32 -> bf16 conversion (all 9 segments, one dispatch) ----------------
// dst (ws) is the contiguous concatenation [query | enc | glob | qw kw vw gkw gvw ow] in bf16.
// Block-uniform segment select: all boundaries are multiples of 256 float4.
__global__ __launch_bounds__(256) void cvt_all_kernel(const float* __restrict__ q, const float* __restrict__ e,
                                                      const float* __restrict__ g, const float* __restrict__ w0,
                                                      const float* __restrict__ w1, const float* __restrict__ w2,
                                                      const float* __restrict__ w3, const float* __restrict__ w4,
                                                      const float* __restrict__ w5, u16* __restrict__ dst) {
  int blk = blockIdx.x;
  const float* src;
  int sblk;  // segment start block
  if (blk < 8192) { src = q; sblk = 0; }
  else if (blk < 16384) { src = e; sblk = 8192; }
  else if (blk < 16512) { src = g; sblk = 16384; }
  else if (blk < 17536) { src = w0; sblk = 16512; }
  else if (blk < 18560) { src = w1; sblk = 17536; }
  else if (blk < 19584) { src = w2; sblk = 18560; }
  else if (blk < 20608) { src = w3; sblk = 19584; }
  else if (blk < 21632) { src = w4; sblk = 20608; }
  else { src = w5; sblk = 21632; }
  int li = (blk - sblk) * 256 + threadIdx.x;        // float4 index within segment
  size_t gi = (size_t)blk * 256 + threadIdx.x;      // float4 index within concatenation
  float4 v = ((const float4*)src)[li];
  uint2 o;
  o.x = (u32)f2bf(v.x) | ((u32)f2bf(v.y) << 16);
  o.y = (u32)f2bf(v.z) | ((u32)f2bf(v.w) << 16);
  ((uint2*)dst)[gi] = o;
}

// ---------------- bf16 GEMM: C[M,N] = A[M,K] * Bt[N,K]^T + bias ----------------
// MODE 0: store bf16; MODE 1: store bf16 scaled by 0.125*log2(e); MODE 2: store f32;
// MODE 3: bf16 dual-output (col<1024 -> out/bias, col>=1024 -> out+split-1024/bias2)
// v3: double-buffered LDS + single barrier per K-step (prefetch hides under MFMA);
//     source-pre-swizzled staging kills the 8-way LDS read conflict (bits 4-5 ^= row bits 1-2);
//     C^T accumulation (swapped mfma operands) -> wide vectorized epilogue stores.
template <int MODE>
__global__ __launch_bounds__(256) void gemm_kernel(const u16* __restrict__ A, const u16* __restrict__ Bt,
                                                   const float* __restrict__ bias, const float* __restrict__ bias2,
                                                   size_t split, void* __restrict__ out) {
  __shared__ char lds[32768];  // As dbuf [0,16K), Bs dbuf [16K,32K); 8KB per tile
  char* As = lds;
  char* Bs = lds + 16384;
  const int tid = threadIdx.x;
  const int lane = tid & 63;
  const int wv = tid >> 6;
  const int wr = wv >> 1, wc = wv & 1;
  const int l15 = lane & 15, kg = lane >> 4;
  const int row0 = blockIdx.x * 128;
  const int col0 = blockIdx.y * 128;

  f32x4 acc[4][4];
#pragma unroll
  for (int i = 0; i < 4; i++)
#pragma unroll
    for (int j = 0; j < 4; j++)
#pragma unroll
      for (int r = 0; r < 4; r++) acc[i][j][r] = 0.f;

  const char* Abase = (const char*)A;
  const char* Bbase = (const char*)Bt;

  // staging geometry: linear LDS dest (required by global_load_lds); the global SOURCE byte
  // column is pre-swizzled so that LDS[p] holds logical p ^ (((p>>7)&3)<<4) (involution).
  const int kb = 16 * ((lane & 3) ^ ((lane >> 3) & 3));  // swizzled byte-within-row, [0,64)
  auto stage = [&](int bufsel, int k0) {
#pragma unroll
    for (int c = 0; c < 2; c++) {
      int arow = wv * 32 + c * 16 + (lane >> 2);
      int dsto = bufsel * 8192 + wv * 2048 + c * 1024 + lane * 16;
      const char* ga = Abase + ((size_t)(row0 + arow) * 2048 + (size_t)k0 * 2 + kb);
      __builtin_amdgcn_global_load_lds((const __attribute__((address_space(1))) void*)ga,
                                       (__attribute__((address_space(3))) void*)(As + dsto), 16, 0, 0);
      const char* gb = Bbase + ((size_t)(col0 + arow) * 2048 + (size_t)k0 * 2 + kb);
      __builtin_amdgcn_global_load_lds((const __attribute__((address_space(1))) void*)gb,
                                       (__attribute__((address_space(3))) void*)(Bs + dsto), 16, 0, 0);
    }
  };

  stage(0, 0);
  __syncthreads();  // buf0 ready

  for (int it = 0; it < 32; ++it) {
    const int cur = it & 1;
    if (it + 1 < 32) stage(cur ^ 1, (it + 1) * 32);  // prefetch overlaps this iter's compute

    const char* Ab = As + cur * 8192;
    const char* Bb = Bs + cur * 8192;
    bf16x8 af[4], bfv[4];
#pragma unroll
    for (int mi = 0; mi < 4; mi++) {
      int row = wr * 64 + mi * 16 + l15;
      af[mi] = *(const bf16x8*)(Ab + ((row * 64 + kg * 16) ^ ((row & 6) << 3)));
    }
#pragma unroll
    for (int ni = 0; ni < 4; ni++) {
      int row = wc * 64 + ni * 16 + l15;
      bfv[ni] = *(const bf16x8*)(Bb + ((row * 64 + kg * 16) ^ ((row & 6) << 3)));
    }
    __builtin_amdgcn_s_setprio(1);
#pragma unroll
    for (int mi = 0; mi < 4; mi++)
#pragma unroll
      for (int ni = 0; ni < 4; ni++)
        // swapped operands: result row-space = Bt row (= C col), col-space = A row (= C row)
        acc[mi][ni] = __builtin_amdgcn_mfma_f32_16x16x32_bf16(bfv[ni], af[mi], acc[mi][ni], 0, 0, 0);
    __builtin_amdgcn_s_setprio(0);
    __syncthreads();  // drains prefetch (vmcnt) + protects buf[cur] before overwrite
  }

  // epilogue: thread holds C[row = row0+wr*64+mi*16+l15][col = col0+wc*64+ni*16+kg*4 + r]
  const float* bp = bias;
  size_t obase = 0;
  if (MODE == 3 && col0 >= 1024) {
    bp = bias2 - 1024;
    obase = split - 1024;
  }
  float4 bv4[4];
#pragma unroll
  for (int ni = 0; ni < 4; ni++) bv4[ni] = *(const float4*)&bp[col0 + wc * 64 + ni * 16 + kg * 4];
#pragma unroll
  for (int mi = 0; mi < 4; mi++) {
    size_t grow = (size_t)(row0 + wr * 64 + mi * 16 + l15);
#pragma unroll
    for (int ni = 0; ni < 4; ni++) {
      int gcol = col0 + wc * 64 + ni * 16 + kg * 4;
      float v0 = acc[mi][ni][0] + bv4[ni].x;
      float v1 = acc[mi][ni][1] + bv4[ni].y;
      float v2 = acc[mi][ni][2] + bv4[ni].z;
      float v3 = acc[mi][ni][3] + bv4[ni].w;
      if (MODE == 1) {
        v0 *= 0.18033688011112042f; v1 *= 0.18033688011112042f;  // (1/8)*log2(e)
        v2 *= 0.18033688011112042f; v3 *= 0.18033688011112042f;
      }
      if (MODE == 2) {
        float4 fo = {v0, v1, v2, v3};
        *(float4*)&((float*)out)[grow * 1024 + gcol] = fo;
      } else {
        uint2 o;
        asm("v_cvt_pk_bf16_f32 %0, %1, %2" : "=v"(o.x) : "v"(v0), "v"(v1));
        asm("v_cvt_pk_bf16_f32 %0, %1, %2" : "=v"(o.y) : "v"(v2), "v"(v3));
        *(uint2*)&((u16*)out)[obase + grow * 1024 + gcol] = o;
      }
    }
  }
}

// ---------------- fused attention ----------------
// (unchanged from round-2 PASSED kernel)
__global__ __launch_bounds__(512, 4) void attn_kernel(const u16* __restrict__ q_bf, const u16* __restrict__ k_bf,
                                                      const u16* __restrict__ v_bf, const u16* __restrict__ gk_bf,
                                                      const u16* __restrict__ gv_bf, u16* __restrict__ ao,
                                                      const int* __restrict__ rptr) {
  __shared__ u16 smem[16384];
  const int c = blockIdx.x, h = blockIdx.y, b = blockIdx.z;
  const int tid = threadIdx.x;
  const int lane = tid & 63, wv = tid >> 6;
  const int l31 = lane & 31, half = lane >> 5;
  const int t0 = c * CHUNK_;

  int rr = rptr[0];
  int centert = c * CHUNK_ + CHUNK_ / 2;
  int expected = (int)((float)centert / (float)rr);
  expected = min(max(expected, 0), S_ - 1);
  int ws0 = min(max(expected - W_ / 2, 0), S_ - W_);

  bf16x8 qf[4];
  {
    const u16* qrow = q_bf + ((size_t)(b * T_ + t0 + wv * 32 + l31)) * D_ + h * 64 + half * 8;
#pragma unroll
    for (int s = 0; s < 4; s++) qf[s] = *(const bf16x8*)(qrow + s * 16);
  }

  const int skey = (tid & 255) >> 3, shq = tid & 7;
  const bool isK = tid < 256;

  auto load_tile = [&](int j) -> uint4 {
    const u16* base;
    size_t row;
    if (j < 2) {
      base = isK ? gk_bf : gv_bf;
      row = (size_t)(b * G_ + j * 32 + skey);
    } else {
      base = isK ? k_bf : v_bf;
      row = (size_t)(b * S_ + ws0 + (j - 2) * 32 + skey);
    }
    return *(const uint4*)(base + row * D_ + h * 64 + shq * 8);
  };

  f32x16 oacc[2];
#pragma unroll
  for (int i = 0; i < 2; i++)
#pragma unroll
    for (int r = 0; r < 16; r++) oacc[i][r] = 0.f;
  float mrun = -1e30f, lsum = 0.f;

  uint4 stg = load_tile(0);

  for (int j = 0; j < NT_; j++) {
    const int bsel = j & 1;
    if (isK) {
      *(uint4*)((char*)smem + bsel * 4096 + ((skey * 128 + shq * 16) ^ ((skey & 7) << 4))) = stg;
    } else {
      const u16* pv = (const u16*)&stg;
      char* bp = (char*)smem + 8192 + bsel * 5248 + shq * 656 + skey * 2;  // 656 = 8*80+16 (row skew)
#pragma unroll
      for (int e = 0; e < 8; e++) *(u16*)(bp + e * 80) = pv[e];
    }
    if (j + 1 < NT_) stg = load_tile(j + 1);
    __syncthreads();

    const int kbase = bsel * 4096;
    const int vtb = 8192 + bsel * 5248;

    f32x16 sacc;
#pragma unroll
    for (int r = 0; r < 16; r++) sacc[r] = 0.f;
    __builtin_amdgcn_s_setprio(1);
#pragma unroll
    for (int s = 0; s < 4; s++) {
      int kb = kbase + ((l31 * 128 + half * 16 + s * 32) ^ ((l31 & 7) << 4));
      bf16x8 kf = *(const bf16x8*)((char*)smem + kb);
      sacc = __builtin_amdgcn_mfma_f32_32x32x16_bf16(kf, qf[s], sacc, 0, 0, 0);
    }
    __builtin_amdgcn_s_setprio(0);

    float t0m = fmaxf(fmaxf(sacc[0], sacc[1]), sacc[2]);
    float t1m = fmaxf(fmaxf(sacc[3], sacc[4]), sacc[5]);
    float t2m = fmaxf(fmaxf(sacc[6], sacc[7]), sacc[8]);
    float t3m = fmaxf(fmaxf(sacc[9], sacc[10]), sacc[11]);
    float t4m = fmaxf(fmaxf(sacc[12], sacc[13]), sacc[14]);
    float tmax = fmaxf(fmaxf(fmaxf(t0m, t1m), fmaxf(t2m, t3m)), fmaxf(t4m, sacc[15]));
    tmax = fmaxf(tmax, __shfl_xor(tmax, 32));
    if (__any(tmax > mrun + 8.f)) {
      float mnew = fmaxf(mrun, tmax);
      float fac = __builtin_amdgcn_exp2f(mrun - mnew);
      mrun = mnew;
      lsum *= fac;
#pragma unroll
      for (int i = 0; i < 2; i++)
#pragma unroll
        for (int r = 0; r < 16; r++) oacc[i][r] *= fac;
    }
    float p[16];
#pragma unroll
    for (int r = 0; r < 16; r++) p[r] = __builtin_amdgcn_exp2f(sacc[r] - mrun);
    float s0s = (p[0] + p[1]) + (p[2] + p[3]);
    float s1s = (p[4] + p[5]) + (p[6] + p[7]);
    float s2s = (p[8] + p[9]) + (p[10] + p[11]);
    float s3s = (p[12] + p[13]) + (p[14] + p[15]);
    float tsum = (s0s + s1s) + (s2s + s3s);
    tsum += __shfl_xor(tsum, 32);
    lsum += tsum;

    u32 xs[8], px[8];
#pragma unroll
    for (int i = 0; i < 8; i++)
      asm("v_cvt_pk_bf16_f32 %0, %1, %2" : "=v"(xs[i]) : "v"(p[2 * i]), "v"(p[2 * i + 1]));
#pragma unroll
    for (int i = 0; i < 8; i++) px[i] = (u32)__shfl_xor((int)xs[i], 32);
    u32 Bk[2][4];
    Bk[0][0] = half ? px[2] : xs[0];
    Bk[0][1] = half ? px[3] : xs[1];
    Bk[0][2] = half ? xs[2] : px[0];
    Bk[0][3] = half ? xs[3] : px[1];
    Bk[1][0] = half ? px[6] : xs[4];
    Bk[1][1] = half ? px[7] : xs[5];
    Bk[1][2] = half ? xs[6] : px[4];
    Bk[1][3] = half ? xs[7] : px[5];

    int vro = vtb + l31 * 80 + ((l31 >> 3) << 4) + half * 16;
    __builtin_amdgcn_s_setprio(1);
#pragma unroll
    for (int hdf = 0; hdf < 2; hdf++) {
#pragma unroll
      for (int ks = 0; ks < 2; ks++) {
        bf16x8 vf = *(const bf16x8*)((const char*)smem + vro + hdf * 2624 + ks * 32);  // 2624 = 32*80+64
        uint4 u4;
        u4.x = Bk[ks][0]; u4.y = Bk[ks][1]; u4.z = Bk[ks][2]; u4.w = Bk[ks][3];
        bf16x8 pb = __builtin_bit_cast(bf16x8, u4);
        oacc[hdf] = __builtin_amdgcn_mfma_f32_32x32x16_bf16(vf, pb, oacc[hdf], 0, 0, 0);
      }
    }
    __builtin_amdgcn_s_setprio(0);
  }

  __syncthreads();
  float inv = 1.f / lsum;
#pragma unroll
  for (int hdf = 0; hdf < 2; hdf++) {
#pragma unroll
    for (int a = 0; a < 4; a++) {
      float f0 = oacc[hdf][4 * a] * inv, f1 = oacc[hdf][4 * a + 1] * inv;
      float f2 = oacc[hdf][4 * a + 2] * inv, f3 = oacc[hdf][4 * a + 3] * inv;
      uint2 o;
      asm("v_cvt_pk_bf16_f32 %0, %1, %2" : "=v"(o.x) : "v"(f0), "v"(f1));
      asm("v_cvt_pk_bf16_f32 %0, %1, %2" : "=v"(o.y) : "v"(f2), "v"(f3));
      int off = wv * 4096 + l31 * 128 + ((16 * a + 8 * half + 64 * hdf) ^ ((l31 & 7) << 4));
      *(uint2*)((char*)smem + off) = o;
    }
  }
  __syncthreads();
#pragma unroll
  for (int it = 0; it < 4; it++) {
    int byteo = (tid + it * 512) * 16;
    int row = byteo >> 7;
    int colb = byteo & 127;
    uint4 vv = *(const uint4*)((const char*)smem + row * 128 + (colb ^ ((row & 7) << 4)));
    *(uint4*)(ao + ((size_t)(b * T_ + t0 + row)) * D_ + h * 64 + (colb >> 1)) = vv;
  }
}

extern "C" void kernel_launch(void* const* d_in, const int* in_sizes, int n_in,
                              void* d_out, int out_size, void* d_ws, size_t ws_size,
                              hipStream_t stream) {
  (void)in_sizes; (void)n_in; (void)out_size; (void)ws_size;
  const float* query = (const float*)d_in[0];
  const float* enc = (const float*)d_in[1];
  const float* glob = (const float*)d_in[2];
  const float* qw = (const float*)d_in[3];
  const float* qb = (const float*)d_in[4];
  const float* kw = (const float*)d_in[5];
  const float* kb = (const float*)d_in[6];
  const float* vw = (const float*)d_in[7];
  const float* vb = (const float*)d_in[8];
  const float* gkw = (const float*)d_in[9];
  const float* gkb = (const float*)d_in[10];
  const float* gvw = (const float*)d_in[11];
  const float* gvb = (const float*)d_in[12];
  const float* ow = (const float*)d_in[13];
  const float* ob = (const float*)d_in[14];
  const int* rp = (const int*)d_in[15];

  const size_t NQ = (size_t)B_ * T_ * D_;   // 8388608
  const size_t NG = (size_t)B_ * G_ * D_;   // 131072
  const size_t NW = (size_t)D_ * D_;        // 1048576

  u16* ws = (u16*)d_ws;
  u16* qx = ws;                // bf16 query
  u16* ex = qx + NQ;           // bf16 encoder_out
  u16* gx = ex + NQ;           // bf16 global_tokens
  u16* wgt = gx + NG;          // 6 weights bf16 (qw,kw,vw,gkw,gvw,ow) — contiguous
  u16* q_bf = wgt + 6 * NW;    // projected q (pre-scaled by 0.125*log2e)
  u16* k_bf = q_bf + NQ;
  u16* v_bf = k_bf + NQ;       // contiguous after k_bf (fused K|V gemm)
  u16* gk_bf = v_bf + NQ;
  u16* gv_bf = gk_bf + NG;     // contiguous after gk_bf (fused GK|GV gemm)
  u16* ao = gv_bf + NG;        // attention output bf16 [B*T, D]

  // one fused conversion dispatch: 8192+8192+128+6*1024 = 22656 blocks
  cvt_all_kernel<<<22656, 256, 0, stream>>>(query, enc, glob, qw, kw, vw, gkw, gvw, ow, ws);

  gemm_kernel<1><<<dim3(64, 8), 256, 0, stream>>>(qx, wgt + 0 * NW, qb, qb, 0, q_bf);
  // fused K|V projection: Bt rows [0,2048) span kw then vw; outputs k_bf then v_bf
  gemm_kernel<3><<<dim3(64, 16), 256, 0, stream>>>(ex, wgt + 1 * NW, kb, vb, NQ, k_bf);
  // fused GK|GV projection
  gemm_kernel<3><<<dim3(1, 16), 256, 0, stream>>>(gx, wgt + 3 * NW, gkb, gvb, NG, gk_bf);

  attn_kernel<<<dim3(NC_, H_, B_), 512, 0, stream>>>(q_bf, k_bf, v_bf, gk_bf, gv_bf, ao, rp);

  gemm_kernel<2><<<dim3(64, 8), 256, 0, stream>>>(ao, wgt + 5 * NW, ob, ob, 0, d_out);
}

// Round 4
// 164.249 us; speedup vs baseline: 1.3445x; 1.0421x over previous
//
#include <hip/hip_runtime.h>

typedef unsigned short u16;
typedef unsigned int u32;
typedef __attribute__((ext_vector_type(4))) float f32x4;
typedef __attribute__((ext_vector_type(16))) float f32x16;
typedef __attribute__((ext_vector_type(8))) short bf16x8;

constexpr int B_ = 2, T_ = 4096, S_ = 4096, G_ = 64, D_ = 1024, H_ = 16, W_ = 512, CHUNK_ = 256;
constexpr int NC_ = T_ / CHUNK_;   // 16 chunks
constexpr int NT_ = (G_ + W_) / 32; // 18 key tiles of 32 (2 global + 16 window)

__device__ __forceinline__ u16 f2bf(float x) {
  u32 u = __builtin_bit_cast(u32, x);
  return (u16)((u + 0x7FFFu + ((u >> 16) & 1u)) >> 16);
}

// ---------------- fused f32 -> bf16 conversion (all 9 segments, one dispatch) ----------------
__global__ __launch_bounds__(256) void cvt_all_kernel(const float* __restrict__ q, const float* __restrict__ e,
                                                      const float* __restrict__ g, const float* __restrict__ w0,
                                                      const float* __restrict__ w1, const float* __restrict__ w2,
                                                      const float* __restrict__ w3, const float* __restrict__ w4,
                                                      const float* __restrict__ w5, u16* __restrict__ dst) {
  int blk = blockIdx.x;
  const float* src;
  int sblk;  // segment start block
  if (blk < 8192) { src = q; sblk = 0; }
  else if (blk < 16384) { src = e; sblk = 8192; }
  else if (blk < 16512) { src = g; sblk = 16384; }
  else if (blk < 17536) { src = w0; sblk = 16512; }
  else if (blk < 18560) { src = w1; sblk = 17536; }
  else if (blk < 19584) { src = w2; sblk = 18560; }
  else if (blk < 20608) { src = w3; sblk = 19584; }
  else if (blk < 21632) { src = w4; sblk = 20608; }
  else { src = w5; sblk = 21632; }
  int li = (blk - sblk) * 256 + threadIdx.x;        // float4 index within segment
  size_t gi = (size_t)blk * 256 + threadIdx.x;      // float4 index within concatenation
  float4 v = ((const float4*)src)[li];
  uint2 o;
  o.x = (u32)f2bf(v.x) | ((u32)f2bf(v.y) << 16);
  o.y = (u32)f2bf(v.z) | ((u32)f2bf(v.w) << 16);
  ((uint2*)dst)[gi] = o;
}

// ---------------- bf16 GEMM 128x128 (v3, passing): used for Q, O, GK|GV ----------------
// MODE 0: bf16; MODE 1: bf16 scaled by 0.125*log2(e); MODE 2: f32;
// MODE 3: bf16 dual-output (col<1024 -> out/bias, col>=1024 -> out+split-1024/bias2)
template <int MODE>
__global__ __launch_bounds__(256) void gemm_kernel(const u16* __restrict__ A, const u16* __restrict__ Bt,
                                                   const float* __restrict__ bias, const float* __restrict__ bias2,
                                                   size_t split, void* __restrict__ out) {
  __shared__ char lds[32768];  // As dbuf [0,16K), Bs dbuf [16K,32K); 8KB per tile
  char* As = lds;
  char* Bs = lds + 16384;
  const int tid = threadIdx.x;
  const int lane = tid & 63;
  const int wv = tid >> 6;
  const int wr = wv >> 1, wc = wv & 1;
  const int l15 = lane & 15, kg = lane >> 4;
  const int row0 = blockIdx.x * 128;
  const int col0 = blockIdx.y * 128;

  f32x4 acc[4][4];
#pragma unroll
  for (int i = 0; i < 4; i++)
#pragma unroll
    for (int j = 0; j < 4; j++)
#pragma unroll
      for (int r = 0; r < 4; r++) acc[i][j][r] = 0.f;

  const char* Abase = (const char*)A;
  const char* Bbase = (const char*)Bt;

  const int kb = 16 * ((lane & 3) ^ ((lane >> 3) & 3));  // source-pre-swizzled byte-within-row
  auto stage = [&](int bufsel, int k0) {
#pragma unroll
    for (int c = 0; c < 2; c++) {
      int arow = wv * 32 + c * 16 + (lane >> 2);
      int dsto = bufsel * 8192 + wv * 2048 + c * 1024 + lane * 16;
      const char* ga = Abase + ((size_t)(row0 + arow) * 2048 + (size_t)k0 * 2 + kb);
      __builtin_amdgcn_global_load_lds((const __attribute__((address_space(1))) void*)ga,
                                       (__attribute__((address_space(3))) void*)(As + dsto), 16, 0, 0);
      const char* gb = Bbase + ((size_t)(col0 + arow) * 2048 + (size_t)k0 * 2 + kb);
      __builtin_amdgcn_global_load_lds((const __attribute__((address_space(1))) void*)gb,
                                       (__attribute__((address_space(3))) void*)(Bs + dsto), 16, 0, 0);
    }
  };

  stage(0, 0);
  __syncthreads();  // buf0 ready

  for (int it = 0; it < 32; ++it) {
    const int cur = it & 1;
    if (it + 1 < 32) stage(cur ^ 1, (it + 1) * 32);  // prefetch overlaps this iter's compute

    const char* Ab = As + cur * 8192;
    const char* Bb = Bs + cur * 8192;
    bf16x8 af[4], bfv[4];
#pragma unroll
    for (int mi = 0; mi < 4; mi++) {
      int row = wr * 64 + mi * 16 + l15;
      af[mi] = *(const bf16x8*)(Ab + ((row * 64 + kg * 16) ^ ((row & 6) << 3)));
    }
#pragma unroll
    for (int ni = 0; ni < 4; ni++) {
      int row = wc * 64 + ni * 16 + l15;
      bfv[ni] = *(const bf16x8*)(Bb + ((row * 64 + kg * 16) ^ ((row & 6) << 3)));
    }
    __builtin_amdgcn_s_setprio(1);
#pragma unroll
    for (int mi = 0; mi < 4; mi++)
#pragma unroll
      for (int ni = 0; ni < 4; ni++)
        acc[mi][ni] = __builtin_amdgcn_mfma_f32_16x16x32_bf16(bfv[ni], af[mi], acc[mi][ni], 0, 0, 0);
    __builtin_amdgcn_s_setprio(0);
    __syncthreads();  // drains prefetch (vmcnt) + protects buf[cur] before overwrite
  }

  const float* bp = bias;
  size_t obase = 0;
  if (MODE == 3 && col0 >= 1024) {
    bp = bias2 - 1024;
    obase = split - 1024;
  }
  float4 bv4[4];
#pragma unroll
  for (int ni = 0; ni < 4; ni++) bv4[ni] = *(const float4*)&bp[col0 + wc * 64 + ni * 16 + kg * 4];
#pragma unroll
  for (int mi = 0; mi < 4; mi++) {
    size_t grow = (size_t)(row0 + wr * 64 + mi * 16 + l15);
#pragma unroll
    for (int ni = 0; ni < 4; ni++) {
      int gcol = col0 + wc * 64 + ni * 16 + kg * 4;
      float v0 = acc[mi][ni][0] + bv4[ni].x;
      float v1 = acc[mi][ni][1] + bv4[ni].y;
      float v2 = acc[mi][ni][2] + bv4[ni].z;
      float v3 = acc[mi][ni][3] + bv4[ni].w;
      if (MODE == 1) {
        v0 *= 0.18033688011112042f; v1 *= 0.18033688011112042f;  // (1/8)*log2(e)
        v2 *= 0.18033688011112042f; v3 *= 0.18033688011112042f;
      }
      if (MODE == 2) {
        float4 fo = {v0, v1, v2, v3};
        *(float4*)&((float*)out)[grow * 1024 + gcol] = fo;
      } else {
        uint2 o;
        asm("v_cvt_pk_bf16_f32 %0, %1, %2" : "=v"(o.x) : "v"(v0), "v"(v1));
        asm("v_cvt_pk_bf16_f32 %0, %1, %2" : "=v"(o.y) : "v"(v2), "v"(v3));
        *(uint2*)&((u16*)out)[obase + grow * 1024 + gcol] = o;
      }
    }
  }
}

// ---------------- bf16 GEMM 256x256 deep-pipelined (for K|V projection) ----------------
// 512 thr = 8 waves (2M x 4N), per-wave output 128x64. BK=32. 3-buffer LDS ring (96KB),
// prefetch issued 2 tiles ahead; counted s_waitcnt vmcnt(4) before the tile-boundary raw
// s_barrier (never 0 until the drain tile) so loads stay in flight across barriers.
// 2 phases of 16 MFMA per K-step with per-phase barriers (ds_read || gload_lds || MFMA
// interleave across waves). T1 XCD swizzle: each XCD owns one 256-col B panel.
// Buffer hazards: tile t computes buf[t%3], stages buf[(t+2)%3] (last read at t-1,
// reads done before t-1's trailing barrier); vmcnt(4) before the trailing barrier
// guarantees all threads' stage(t+1) landed before anyone reads it.
template <int MODE>
__global__ __launch_bounds__(512, 2) void gemm256_kernel(const u16* __restrict__ A, const u16* __restrict__ Bt,
                                                         const float* __restrict__ bias, const float* __restrict__ bias2,
                                                         size_t split, void* __restrict__ out) {
  __shared__ char lds[98304];  // A ring [0,48K): 3 x 16KB; B ring [48K,96K): 3 x 16KB
  const int tid = threadIdx.x;
  const int lane = tid & 63;
  const int wid = tid >> 6;
  const int wm = wid >> 2, wn = wid & 3;
  const int l15 = lane & 15, kg = lane >> 4;
  const int bid = blockIdx.x;
  const int swz = (bid & 7) * 32 + (bid >> 3);  // 256 blocks: bijective; XCD x -> col panel x
  const int row0 = (swz & 31) * 256;
  const int col0 = (swz >> 5) * 256;

  f32x4 acc[8][4];
#pragma unroll
  for (int i = 0; i < 8; i++)
#pragma unroll
    for (int j = 0; j < 4; j++)
#pragma unroll
      for (int r = 0; r < 4; r++) acc[i][j][r] = 0.f;

  const char* Abase = (const char*)A;
  const char* Bbase = (const char*)Bt;
  // source pre-swizzle: LDS[p] holds logical chunk ((p>>4)&3) ^ ((p>>7)&3) of row p>>6
  const int kb = 16 * ((tid & 3) ^ ((tid >> 3) & 3));
  const int rl0 = tid >> 2;  // staged row (j=0); j=1 adds 128

  auto stageOp = [&](const char* base, int rowbase, int ldsbase, int kt) {
#pragma unroll
    for (int j = 0; j < 2; j++) {
      int dst = ldsbase + tid * 16 + j * 8192;
      const char* g = base + (size_t)(rowbase + rl0 + j * 128) * 2048 + kt * 64 + kb;
      __builtin_amdgcn_global_load_lds((const __attribute__((address_space(1))) void*)g,
                                       (__attribute__((address_space(3))) void*)(lds + dst), 16, 0, 0);
    }
  };

  // prologue: stage tiles 0 and 1; wait tile0 (oldest 4 of 8) landed
  stageOp(Abase, row0, 0, 0);
  stageOp(Bbase, col0, 49152, 0);
  stageOp(Abase, row0, 16384, 1);
  stageOp(Bbase, col0, 49152 + 16384, 1);
  asm volatile("s_waitcnt vmcnt(4)" ::: "memory");
  __builtin_amdgcn_s_barrier();

  int cur = 0, nx = 2;
  for (int t = 0; t < 32; ++t) {
    const char* Ab = lds + cur * 16384;
    const char* Bb = lds + 49152 + cur * 16384;
    bf16x8 bfv[4], af[4];
    // ---- phase 0: read B frags (reused both phases) + A frags mi 0..3; stage A(t+2)
#pragma unroll
    for (int ni = 0; ni < 4; ni++) {
      int r = wn * 64 + ni * 16 + l15;
      bfv[ni] = *(const bf16x8*)(Bb + ((r * 64 + kg * 16) ^ (((r >> 1) & 3) << 4)));
    }
#pragma unroll
    for (int mi = 0; mi < 4; mi++) {
      int r = wm * 128 + mi * 16 + l15;
      af[mi] = *(const bf16x8*)(Ab + ((r * 64 + kg * 16) ^ (((r >> 1) & 3) << 4)));
    }
    if (t + 2 < 32) stageOp(Abase, row0, nx * 16384, t + 2);
    __builtin_amdgcn_s_barrier();
    __builtin_amdgcn_s_setprio(1);
#pragma unroll
    for (int mi = 0; mi < 4; mi++)
#pragma unroll
      for (int ni = 0; ni < 4; ni++)
        acc[mi][ni] = __builtin_amdgcn_mfma_f32_16x16x32_bf16(bfv[ni], af[mi], acc[mi][ni], 0, 0, 0);
    __builtin_amdgcn_s_setprio(0);
    __builtin_amdgcn_s_barrier();
    // ---- phase 1: read A frags mi 4..7; stage B(t+2)
#pragma unroll
    for (int mi = 0; mi < 4; mi++) {
      int r = wm * 128 + (mi + 4) * 16 + l15;
      af[mi] = *(const bf16x8*)(Ab + ((r * 64 + kg * 16) ^ (((r >> 1) & 3) << 4)));
    }
    if (t + 2 < 32) stageOp(Bbase, col0, 49152 + nx * 16384, t + 2);
    __builtin_amdgcn_s_barrier();
    __builtin_amdgcn_s_setprio(1);
#pragma unroll
    for (int mi = 0; mi < 4; mi++)
#pragma unroll
      for (int ni = 0; ni < 4; ni++)
        acc[mi + 4][ni] = __builtin_amdgcn_mfma_f32_16x16x32_bf16(bfv[ni], af[mi], acc[mi + 4][ni], 0, 0, 0);
    __builtin_amdgcn_s_setprio(0);
    // tile boundary: ensure stage(t+1) landed for all threads, allow stage(t+2) in flight
    if (t < 30) {
      asm volatile("s_waitcnt vmcnt(4)" ::: "memory");
    } else if (t == 30) {
      asm volatile("s_waitcnt vmcnt(0)" ::: "memory");
    }
    __builtin_amdgcn_s_barrier();
    cur = cur == 2 ? 0 : cur + 1;
    nx = nx == 2 ? 0 : nx + 1;
  }

  // epilogue (same mapping as v3): C[row0+wm*128+mi*16+l15][col0+wn*64+ni*16+kg*4+r]
  const float* bp = bias;
  size_t obase = 0;
  if (MODE == 3 && col0 >= 1024) {
    bp = bias2 - 1024;
    obase = split - 1024;
  }
  float4 bv4[4];
#pragma unroll
  for (int ni = 0; ni < 4; ni++) bv4[ni] = *(const float4*)&bp[col0 + wn * 64 + ni * 16 + kg * 4];
#pragma unroll
  for (int mi = 0; mi < 8; mi++) {
    size_t grow = (size_t)(row0 + wm * 128 + mi * 16 + l15);
#pragma unroll
    for (int ni = 0; ni < 4; ni++) {
      int gcol = col0 + wn * 64 + ni * 16 + kg * 4;
      float v0 = acc[mi][ni][0] + bv4[ni].x;
      float v1 = acc[mi][ni][1] + bv4[ni].y;
      float v2 = acc[mi][ni][2] + bv4[ni].z;
      float v3 = acc[mi][ni][3] + bv4[ni].w;
      if (MODE == 1) {
        v0 *= 0.18033688011112042f; v1 *= 0.18033688011112042f;
        v2 *= 0.18033688011112042f; v3 *= 0.18033688011112042f;
      }
      if (MODE == 2) {
        float4 fo = {v0, v1, v2, v3};
        *(float4*)&((float*)out)[grow * 1024 + gcol] = fo;
      } else {
        uint2 o;
        asm("v_cvt_pk_bf16_f32 %0, %1, %2" : "=v"(o.x) : "v"(v0), "v"(v1));
        asm("v_cvt_pk_bf16_f32 %0, %1, %2" : "=v"(o.y) : "v"(v2), "v"(v3));
        *(uint2*)&((u16*)out)[obase + grow * 1024 + gcol] = o;
      }
    }
  }
}

// ---------------- fused attention (unchanged, passing) ----------------
__global__ __launch_bounds__(512, 4) void attn_kernel(const u16* __restrict__ q_bf, const u16* __restrict__ k_bf,
                                                      const u16* __restrict__ v_bf, const u16* __restrict__ gk_bf,
                                                      const u16* __restrict__ gv_bf, u16* __restrict__ ao,
                                                      const int* __restrict__ rptr) {
  __shared__ u16 smem[16384];
  const int c = blockIdx.x, h = blockIdx.y, b = blockIdx.z;
  const int tid = threadIdx.x;
  const int lane = tid & 63, wv = tid >> 6;
  const int l31 = lane & 31, half = lane >> 5;
  const int t0 = c * CHUNK_;

  int rr = rptr[0];
  int centert = c * CHUNK_ + CHUNK_ / 2;
  int expected = (int)((float)centert / (float)rr);
  expected = min(max(expected, 0), S_ - 1);
  int ws0 = min(max(expected - W_ / 2, 0), S_ - W_);

  bf16x8 qf[4];
  {
    const u16* qrow = q_bf + ((size_t)(b * T_ + t0 + wv * 32 + l31)) * D_ + h * 64 + half * 8;
#pragma unroll
    for (int s = 0; s < 4; s++) qf[s] = *(const bf16x8*)(qrow + s * 16);
  }

  const int skey = (tid & 255) >> 3, shq = tid & 7;
  const bool isK = tid < 256;

  auto load_tile = [&](int j) -> uint4 {
    const u16* base;
    size_t row;
    if (j < 2) {
      base = isK ? gk_bf : gv_bf;
      row = (size_t)(b * G_ + j * 32 + skey);
    } else {
      base = isK ? k_bf : v_bf;
      row = (size_t)(b * S_ + ws0 + (j - 2) * 32 + skey);
    }
    return *(const uint4*)(base + row * D_ + h * 64 + shq * 8);
  };

  f32x16 oacc[2];
#pragma unroll
  for (int i = 0; i < 2; i++)
#pragma unroll
    for (int r = 0; r < 16; r++) oacc[i][r] = 0.f;
  float mrun = -1e30f, lsum = 0.f;

  uint4 stg = load_tile(0);

  for (int j = 0; j < NT_; j++) {
    const int bsel = j & 1;
    if (isK) {
      *(uint4*)((char*)smem + bsel * 4096 + ((skey * 128 + shq * 16) ^ ((skey & 7) << 4))) = stg;
    } else {
      const u16* pv = (const u16*)&stg;
      char* bp = (char*)smem + 8192 + bsel * 5248 + shq * 656 + skey * 2;  // 656 = 8*80+16 (row skew)
#pragma unroll
      for (int e = 0; e < 8; e++) *(u16*)(bp + e * 80) = pv[e];
    }
    if (j + 1 < NT_) stg = load_tile(j + 1);
    __syncthreads();

    const int kbase = bsel * 4096;
    const int vtb = 8192 + bsel * 5248;

    f32x16 sacc;
#pragma unroll
    for (int r = 0; r < 16; r++) sacc[r] = 0.f;
    __builtin_amdgcn_s_setprio(1);
#pragma unroll
    for (int s = 0; s < 4; s++) {
      int kbx = kbase + ((l31 * 128 + half * 16 + s * 32) ^ ((l31 & 7) << 4));
      bf16x8 kf = *(const bf16x8*)((char*)smem + kbx);
      sacc = __builtin_amdgcn_mfma_f32_32x32x16_bf16(kf, qf[s], sacc, 0, 0, 0);
    }
    __builtin_amdgcn_s_setprio(0);

    float t0m = fmaxf(fmaxf(sacc[0], sacc[1]), sacc[2]);
    float t1m = fmaxf(fmaxf(sacc[3], sacc[4]), sacc[5]);
    float t2m = fmaxf(fmaxf(sacc[6], sacc[7]), sacc[8]);
    float t3m = fmaxf(fmaxf(sacc[9], sacc[10]), sacc[11]);
    float t4m = fmaxf(fmaxf(sacc[12], sacc[13]), sacc[14]);
    float tmax = fmaxf(fmaxf(fmaxf(t0m, t1m), fmaxf(t2m, t3m)), fmaxf(t4m, sacc[15]));
    tmax = fmaxf(tmax, __shfl_xor(tmax, 32));
    if (__any(tmax > mrun + 8.f)) {
      float mnew = fmaxf(mrun, tmax);
      float fac = __builtin_amdgcn_exp2f(mrun - mnew);
      mrun = mnew;
      lsum *= fac;
#pragma unroll
      for (int i = 0; i < 2; i++)
#pragma unroll
        for (int r = 0; r < 16; r++) oacc[i][r] *= fac;
    }
    float p[16];
#pragma unroll
    for (int r = 0; r < 16; r++) p[r] = __builtin_amdgcn_exp2f(sacc[r] - mrun);
    float s0s = (p[0] + p[1]) + (p[2] + p[3]);
    float s1s = (p[4] + p[5]) + (p[6] + p[7]);
    float s2s = (p[8] + p[9]) + (p[10] + p[11]);
    float s3s = (p[12] + p[13]) + (p[14] + p[15]);
    float tsum = (s0s + s1s) + (s2s + s3s);
    tsum += __shfl_xor(tsum, 32);
    lsum += tsum;

    u32 xs[8], px[8];
#pragma unroll
    for (int i = 0; i < 8; i++)
      asm("v_cvt_pk_bf16_f32 %0, %1, %2" : "=v"(xs[i]) : "v"(p[2 * i]), "v"(p[2 * i + 1]));
#pragma unroll
    for (int i = 0; i < 8; i++) px[i] = (u32)__shfl_xor((int)xs[i], 32);
    u32 Bk[2][4];
    Bk[0][0] = half ? px[2] : xs[0];
    Bk[0][1] = half ? px[3] : xs[1];
    Bk[0][2] = half ? xs[2] : px[0];
    Bk[0][3] = half ? xs[3] : px[1];
    Bk[1][0] = half ? px[6] : xs[4];
    Bk[1][1] = half ? px[7] : xs[5];
    Bk[1][2] = half ? xs[6] : px[4];
    Bk[1][3] = half ? xs[7] : px[5];

    int vro = vtb + l31 * 80 + ((l31 >> 3) << 4) + half * 16;
    __builtin_amdgcn_s_setprio(1);
#pragma unroll
    for (int hdf = 0; hdf < 2; hdf++) {
#pragma unroll
      for (int ks = 0; ks < 2; ks++) {
        bf16x8 vf = *(const bf16x8*)((const char*)smem + vro + hdf * 2624 + ks * 32);  // 2624 = 32*80+64
        uint4 u4;
        u4.x = Bk[ks][0]; u4.y = Bk[ks][1]; u4.z = Bk[ks][2]; u4.w = Bk[ks][3];
        bf16x8 pb = __builtin_bit_cast(bf16x8, u4);
        oacc[hdf] = __builtin_amdgcn_mfma_f32_32x32x16_bf16(vf, pb, oacc[hdf], 0, 0, 0);
      }
    }
    __builtin_amdgcn_s_setprio(0);
  }

  __syncthreads();
  float inv = 1.f / lsum;
#pragma unroll
  for (int hdf = 0; hdf < 2; hdf++) {
#pragma unroll
    for (int a = 0; a < 4; a++) {
      float f0 = oacc[hdf][4 * a] * inv, f1 = oacc[hdf][4 * a + 1] * inv;
      float f2 = oacc[hdf][4 * a + 2] * inv, f3 = oacc[hdf][4 * a + 3] * inv;
      uint2 o;
      asm("v_cvt_pk_bf16_f32 %0, %1, %2" : "=v"(o.x) : "v"(f0), "v"(f1));
      asm("v_cvt_pk_bf16_f32 %0, %1, %2" : "=v"(o.y) : "v"(f2), "v"(f3));
      int off = wv * 4096 + l31 * 128 + ((16 * a + 8 * half + 64 * hdf) ^ ((l31 & 7) << 4));
      *(uint2*)((char*)smem + off) = o;
    }
  }
  __syncthreads();
#pragma unroll
  for (int it = 0; it < 4; it++) {
    int byteo = (tid + it * 512) * 16;
    int row = byteo >> 7;
    int colb = byteo & 127;
    uint4 vv = *(const uint4*)((const char*)smem + row * 128 + (colb ^ ((row & 7) << 4)));
    *(uint4*)(ao + ((size_t)(b * T_ + t0 + row)) * D_ + h * 64 + (colb >> 1)) = vv;
  }
}

extern "C" void kernel_launch(void* const* d_in, const int* in_sizes, int n_in,
                              void* d_out, int out_size, void* d_ws, size_t ws_size,
                              hipStream_t stream) {
  (void)in_sizes; (void)n_in; (void)out_size; (void)ws_size;
  const float* query = (const float*)d_in[0];
  const float* enc = (const float*)d_in[1];
  const float* glob = (const float*)d_in[2];
  const float* qw = (const float*)d_in[3];
  const float* qb = (const float*)d_in[4];
  const float* kw = (const float*)d_in[5];
  const float* kb = (const float*)d_in[6];
  const float* vw = (const float*)d_in[7];
  const float* vb = (const float*)d_in[8];
  const float* gkw = (const float*)d_in[9];
  const float* gkb = (const float*)d_in[10];
  const float* gvw = (const float*)d_in[11];
  const float* gvb = (const float*)d_in[12];
  const float* ow = (const float*)d_in[13];
  const float* ob = (const float*)d_in[14];
  const int* rp = (const int*)d_in[15];

  const size_t NQ = (size_t)B_ * T_ * D_;   // 8388608
  const size_t NG = (size_t)B_ * G_ * D_;   // 131072
  const size_t NW = (size_t)D_ * D_;        // 1048576

  u16* ws = (u16*)d_ws;
  u16* qx = ws;                // bf16 query
  u16* ex = qx + NQ;           // bf16 encoder_out
  u16* gx = ex + NQ;           // bf16 global_tokens
  u16* wgt = gx + NG;          // 6 weights bf16 (qw,kw,vw,gkw,gvw,ow) — contiguous
  u16* q_bf = wgt + 6 * NW;    // projected q (pre-scaled by 0.125*log2e)
  u16* k_bf = q_bf + NQ;
  u16* v_bf = k_bf + NQ;       // contiguous after k_bf (fused K|V gemm)
  u16* gk_bf = v_bf + NQ;
  u16* gv_bf = gk_bf + NG;     // contiguous after gk_bf (fused GK|GV gemm)
  u16* ao = gv_bf + NG;        // attention output bf16 [B*T, D]

  // one fused conversion dispatch: 8192+8192+128+6*1024 = 22656 blocks
  cvt_all_kernel<<<22656, 256, 0, stream>>>(query, enc, glob, qw, kw, vw, gkw, gvw, ow, ws);

  gemm_kernel<1><<<dim3(64, 8), 256, 0, stream>>>(qx, wgt + 0 * NW, qb, qb, 0, q_bf);
  // fused K|V projection (deep-pipelined 256x256): M=8192, N=2048 -> 256 blocks (1/CU)
  gemm256_kernel<3><<<256, 512, 0, stream>>>(ex, wgt + 1 * NW, kb, vb, NQ, k_bf);
  // fused GK|GV projection
  gemm_kernel<3><<<dim3(1, 16), 256, 0, stream>>>(gx, wgt + 3 * NW, gkb, gvb, NG, gk_bf);

  attn_kernel<<<dim3(NC_, H_, B_), 512, 0, stream>>>(q_bf, k_bf, v_bf, gk_bf, gv_bf, ao, rp);

  gemm_kernel<2><<<dim3(64, 8), 256, 0, stream>>>(ao, wgt + 5 * NW, ob, ob, 0, d_out);
}

// Round 5
// 151.605 us; speedup vs baseline: 1.4567x; 1.0834x over previous
//
#include <hip/hip_runtime.h>

typedef unsigned short u16;
typedef unsigned int u32;
typedef __attribute__((ext_vector_type(4))) float f32x4;
typedef __attribute__((ext_vector_type(16))) float f32x16;
typedef __attribute__((ext_vector_type(8))) short bf16x8;

constexpr int B_ = 2, T_ = 4096, S_ = 4096, G_ = 64, D_ = 1024, H_ = 16, W_ = 512, CHUNK_ = 256;
constexpr int NC_ = T_ / CHUNK_;   // 16 chunks
constexpr int NT_ = (G_ + W_) / 32; // 18 key tiles of 32 (2 global + 16 window)

__device__ __forceinline__ u16 f2bf(float x) {
  u32 u = __builtin_bit_cast(u32, x);
  return (u16)((u + 0x7FFFu + ((u >> 16) & 1u)) >> 16);
}

// ---------------- fused f32 -> bf16 conversion (all 9 segments, one dispatch) ----------------
__global__ __launch_bounds__(256) void cvt_all_kernel(const float* __restrict__ q, const float* __restrict__ e,
                                                      const float* __restrict__ g, const float* __restrict__ w0,
                                                      const float* __restrict__ w1, const float* __restrict__ w2,
                                                      const float* __restrict__ w3, const float* __restrict__ w4,
                                                      const float* __restrict__ w5, u16* __restrict__ dst) {
  int blk = blockIdx.x;
  const float* src;
  int sblk;  // segment start block
  if (blk < 8192) { src = q; sblk = 0; }
  else if (blk < 16384) { src = e; sblk = 8192; }
  else if (blk < 16512) { src = g; sblk = 16384; }
  else if (blk < 17536) { src = w0; sblk = 16512; }
  else if (blk < 18560) { src = w1; sblk = 17536; }
  else if (blk < 19584) { src = w2; sblk = 18560; }
  else if (blk < 20608) { src = w3; sblk = 19584; }
  else if (blk < 21632) { src = w4; sblk = 20608; }
  else { src = w5; sblk = 21632; }
  int li = (blk - sblk) * 256 + threadIdx.x;        // float4 index within segment
  size_t gi = (size_t)blk * 256 + threadIdx.x;      // float4 index within concatenation
  float4 v = ((const float4*)src)[li];
  uint2 o;
  o.x = (u32)f2bf(v.x) | ((u32)f2bf(v.y) << 16);
  o.y = (u32)f2bf(v.z) | ((u32)f2bf(v.w) << 16);
  ((uint2*)dst)[gi] = o;
}

// ---------------- merged projection GEMM: Q + K|V + GK|GV in one launch ----------------
// Tile 256x128, 256 threads = 4 waves (2M x 2N), per-wave output 128x64 (reuse 2.67 MFMA/read,
// same as the r4 256^2 kernel). LDS 72KB ring of 3 (A 16KB + B 8KB per slot) -> 2 blocks/CU:
// independent blocks cover each other's vmcnt/barrier stalls (the m97 TLP mechanism).
// Staging: global_load_lds with source-pre-swizzled columns (LDS[p] holds chunk ((p>>4)&3)^((p>>7)&3)),
// issued 2 tiles ahead; counted s_waitcnt vmcnt(6) at tile boundary (6 loads per staged tile),
// vmcnt(0) only at the drain tile. Verified structure from round 4, re-parameterized.
// Routing (block-uniform): bid<512 K|V (A=ex, Bt=kw|vw, dual out k_bf/v_bf);
// bid<768 Q (A=qx, Bt=qw, scaled); else GK|GV (A=gx, M=128, dual out gk_bf/gv_bf).
// rp = i&31 -> each XCD touches only 4 A row-panels (2MB, L2-resident).
__global__ __launch_bounds__(256, 2) void proj_kernel(const u16* __restrict__ ex, const u16* __restrict__ qx,
                                                      const u16* __restrict__ gx, const u16* __restrict__ wgt,
                                                      const float* __restrict__ qb, const float* __restrict__ kbias,
                                                      const float* __restrict__ vbias, const float* __restrict__ gkb,
                                                      const float* __restrict__ gvb, u16* __restrict__ q_bf,
                                                      u16* __restrict__ k_bf, u16* __restrict__ gk_bf) {
  __shared__ char lds[73728];  // A ring [0,49152): 3 x 16KB; B ring [49152,73728): 3 x 8KB
  constexpr size_t NW = (size_t)D_ * D_;
  constexpr size_t NQs = (size_t)B_ * T_ * D_;
  constexpr size_t NGs = (size_t)B_ * G_ * D_;
  const int tid = threadIdx.x;
  const int lane = tid & 63;
  const int wid = tid >> 6;
  const int wm = wid >> 1, wn = wid & 1;
  const int l15 = lane & 15, kg = lane >> 4;

  const int bid = blockIdx.x;
  const u16 *A, *Bt;
  const float *b1, *b2;
  u16* out;
  int row0, col0, mloc;
  bool scale = false, dual = false;
  size_t dsplit = 0;
  if (bid < 512) {  // K|V: M=8192, N=2048
    row0 = (bid & 31) * 256; col0 = (bid >> 5) * 128; mloc = 256;
    A = ex; Bt = wgt + NW; b1 = kbias; b2 = vbias; out = k_bf; dsplit = NQs; dual = true;
  } else if (bid < 768) {  // Q: M=8192, N=1024
    int i = bid - 512;
    row0 = (i & 31) * 256; col0 = (i >> 5) * 128; mloc = 256;
    A = qx; Bt = wgt; b1 = qb; b2 = qb; out = q_bf; scale = true;
  } else {  // GK|GV: M=128, N=2048 (rows 128..255 read junk in-bounds, stores guarded)
    int i = bid - 768;
    row0 = 0; col0 = i * 128; mloc = 128;
    A = gx; Bt = wgt + 3 * NW; b1 = gkb; b2 = gvb; out = gk_bf; dsplit = NGs; dual = true;
  }
  const float* bp = b1;
  u16* op = out;
  if (dual && col0 >= 1024) { bp = b2 - 1024; op = out + (dsplit - 1024); }

  f32x4 acc[8][4];
#pragma unroll
  for (int i = 0; i < 8; i++)
#pragma unroll
    for (int j = 0; j < 4; j++)
#pragma unroll
      for (int r = 0; r < 4; r++) acc[i][j][r] = 0.f;

  const char* Abase = (const char*)A;
  const char* Bbase = (const char*)Bt;
  // source pre-swizzle byte column (XOR chunk with row bits 1-2); row = pass*64 + tid>>2
  const int swb = 16 * ((tid & 3) ^ ((tid >> 3) & 3));

  auto stageA = [&](int slot, int kt) {
#pragma unroll
    for (int p = 0; p < 4; p++) {
      int dst = slot * 16384 + p * 4096 + tid * 16;
      const char* g = Abase + (size_t)(row0 + p * 64 + (tid >> 2)) * 2048 + kt * 64 + swb;
      __builtin_amdgcn_global_load_lds((const __attribute__((address_space(1))) void*)g,
                                       (__attribute__((address_space(3))) void*)(lds + dst), 16, 0, 0);
    }
  };
  auto stageB = [&](int slot, int kt) {
#pragma unroll
    for (int p = 0; p < 2; p++) {
      int dst = 49152 + slot * 8192 + p * 4096 + tid * 16;
      const char* g = Bbase + (size_t)(col0 + p * 64 + (tid >> 2)) * 2048 + kt * 64 + swb;
      __builtin_amdgcn_global_load_lds((const __attribute__((address_space(1))) void*)g,
                                       (__attribute__((address_space(3))) void*)(lds + dst), 16, 0, 0);
    }
  };

  // prologue: stage tiles 0,1 (12 loads); vmcnt(6) -> tile0's 6 loads landed
  stageA(0, 0); stageB(0, 0);
  stageA(1, 1); stageB(1, 1);
  asm volatile("s_waitcnt vmcnt(6)" ::: "memory");
  __builtin_amdgcn_s_barrier();

  int cur = 0, nx = 2;
  for (int t = 0; t < 32; ++t) {
    const char* Ab = lds + cur * 16384;
    const char* Bb = lds + 49152 + cur * 8192;
    bf16x8 bfv[2], af[4];
    // ---- phase 0: read B frags (reused both phases) + A frags mi 0..3; stage A(t+2)
#pragma unroll
    for (int ni = 0; ni < 2; ni++) {
      int r = wn * 64 + ni * 16 + l15;  // note: 4 ni of 16 cols = 64; split 2+2 below
      (void)r;
    }
    bf16x8 bq[4];
#pragma unroll
    for (int ni = 0; ni < 4; ni++) {
      int r = wn * 64 + ni * 16 + l15;
      bq[ni] = *(const bf16x8*)(Bb + ((r * 64 + kg * 16) ^ (((r >> 1) & 3) << 4)));
    }
#pragma unroll
    for (int mi = 0; mi < 4; mi++) {
      int r = wm * 128 + mi * 16 + l15;
      af[mi] = *(const bf16x8*)(Ab + ((r * 64 + kg * 16) ^ (((r >> 1) & 3) << 4)));
    }
    if (t + 2 < 32) stageA(nx, t + 2);
    __builtin_amdgcn_s_barrier();
    __builtin_amdgcn_s_setprio(1);
#pragma unroll
    for (int mi = 0; mi < 4; mi++)
#pragma unroll
      for (int ni = 0; ni < 4; ni++)
        acc[mi][ni] = __builtin_amdgcn_mfma_f32_16x16x32_bf16(bq[ni], af[mi], acc[mi][ni], 0, 0, 0);
    __builtin_amdgcn_s_setprio(0);
    __builtin_amdgcn_s_barrier();
    // ---- phase 1: read A frags mi 4..7; stage B(t+2)
#pragma unroll
    for (int mi = 0; mi < 4; mi++) {
      int r = wm * 128 + (mi + 4) * 16 + l15;
      af[mi] = *(const bf16x8*)(Ab + ((r * 64 + kg * 16) ^ (((r >> 1) & 3) << 4)));
    }
    if (t + 2 < 32) stageB(nx, t + 2);
    __builtin_amdgcn_s_barrier();
    __builtin_amdgcn_s_setprio(1);
#pragma unroll
    for (int mi = 0; mi < 4; mi++)
#pragma unroll
      for (int ni = 0; ni < 4; ni++)
        acc[mi + 4][ni] = __builtin_amdgcn_mfma_f32_16x16x32_bf16(bq[ni], af[mi], acc[mi + 4][ni], 0, 0, 0);
    __builtin_amdgcn_s_setprio(0);
    // tile boundary: stage(t+1) landed for all (vmcnt(6) = only stage(t+2)'s 6 in flight)
    if (t < 30) {
      asm volatile("s_waitcnt vmcnt(6)" ::: "memory");
    } else if (t == 30) {
      asm volatile("s_waitcnt vmcnt(0)" ::: "memory");
    }
    __builtin_amdgcn_s_barrier();
    cur = cur == 2 ? 0 : cur + 1;
    nx = nx == 2 ? 0 : nx + 1;
  }

  // epilogue: C[row0+wm*128+mi*16+l15][col0+wn*64+ni*16+kg*4+r], store guarded by mloc
  float4 bv4[4];
#pragma unroll
  for (int ni = 0; ni < 4; ni++) bv4[ni] = *(const float4*)&bp[col0 + wn * 64 + ni * 16 + kg * 4];
#pragma unroll
  for (int mi = 0; mi < 8; mi++) {
    int rloc = wm * 128 + mi * 16 + l15;
    if (rloc >= mloc) continue;  // wave-uniform (mloc=128 cuts exactly wm==1)
    size_t grow = (size_t)(row0 + rloc);
#pragma unroll
    for (int ni = 0; ni < 4; ni++) {
      int gcol = col0 + wn * 64 + ni * 16 + kg * 4;
      float v0 = acc[mi][ni][0] + bv4[ni].x;
      float v1 = acc[mi][ni][1] + bv4[ni].y;
      float v2 = acc[mi][ni][2] + bv4[ni].z;
      float v3 = acc[mi][ni][3] + bv4[ni].w;
      if (scale) {
        v0 *= 0.18033688011112042f; v1 *= 0.18033688011112042f;  // (1/8)*log2(e)
        v2 *= 0.18033688011112042f; v3 *= 0.18033688011112042f;
      }
      uint2 o;
      asm("v_cvt_pk_bf16_f32 %0, %1, %2" : "=v"(o.x) : "v"(v0), "v"(v1));
      asm("v_cvt_pk_bf16_f32 %0, %1, %2" : "=v"(o.y) : "v"(v2), "v"(v3));
      *(uint2*)&op[grow * 1024 + gcol] = o;
    }
  }
}

// ---------------- bf16 GEMM 128x128 (v3, passing): used for O projection ----------------
// MODE 2: f32 out (only instantiated mode)
template <int MODE>
__global__ __launch_bounds__(256) void gemm_kernel(const u16* __restrict__ A, const u16* __restrict__ Bt,
                                                   const float* __restrict__ bias, const float* __restrict__ bias2,
                                                   size_t split, void* __restrict__ out) {
  __shared__ char lds[32768];
  char* As = lds;
  char* Bs = lds + 16384;
  const int tid = threadIdx.x;
  const int lane = tid & 63;
  const int wv = tid >> 6;
  const int wr = wv >> 1, wc = wv & 1;
  const int l15 = lane & 15, kg = lane >> 4;
  const int row0 = blockIdx.x * 128;
  const int col0 = blockIdx.y * 128;

  f32x4 acc[4][4];
#pragma unroll
  for (int i = 0; i < 4; i++)
#pragma unroll
    for (int j = 0; j < 4; j++)
#pragma unroll
      for (int r = 0; r < 4; r++) acc[i][j][r] = 0.f;

  const char* Abase = (const char*)A;
  const char* Bbase = (const char*)Bt;

  const int kb = 16 * ((lane & 3) ^ ((lane >> 3) & 3));
  auto stage = [&](int bufsel, int k0) {
#pragma unroll
    for (int c = 0; c < 2; c++) {
      int arow = wv * 32 + c * 16 + (lane >> 2);
      int dsto = bufsel * 8192 + wv * 2048 + c * 1024 + lane * 16;
      const char* ga = Abase + ((size_t)(row0 + arow) * 2048 + (size_t)k0 * 2 + kb);
      __builtin_amdgcn_global_load_lds((const __attribute__((address_space(1))) void*)ga,
                                       (__attribute__((address_space(3))) void*)(As + dsto), 16, 0, 0);
      const char* gb = Bbase + ((size_t)(col0 + arow) * 2048 + (size_t)k0 * 2 + kb);
      __builtin_amdgcn_global_load_lds((const __attribute__((address_space(1))) void*)gb,
                                       (__attribute__((address_space(3))) void*)(Bs + dsto), 16, 0, 0);
    }
  };

  stage(0, 0);
  __syncthreads();

  for (int it = 0; it < 32; ++it) {
    const int cur = it & 1;
    if (it + 1 < 32) stage(cur ^ 1, (it + 1) * 32);

    const char* Ab = As + cur * 8192;
    const char* Bb = Bs + cur * 8192;
    bf16x8 af[4], bfv[4];
#pragma unroll
    for (int mi = 0; mi < 4; mi++) {
      int row = wr * 64 + mi * 16 + l15;
      af[mi] = *(const bf16x8*)(Ab + ((row * 64 + kg * 16) ^ ((row & 6) << 3)));
    }
#pragma unroll
    for (int ni = 0; ni < 4; ni++) {
      int row = wc * 64 + ni * 16 + l15;
      bfv[ni] = *(const bf16x8*)(Bb + ((row * 64 + kg * 16) ^ ((row & 6) << 3)));
    }
    __builtin_amdgcn_s_setprio(1);
#pragma unroll
    for (int mi = 0; mi < 4; mi++)
#pragma unroll
      for (int ni = 0; ni < 4; ni++)
        acc[mi][ni] = __builtin_amdgcn_mfma_f32_16x16x32_bf16(bfv[ni], af[mi], acc[mi][ni], 0, 0, 0);
    __builtin_amdgcn_s_setprio(0);
    __syncthreads();
  }

  const float* bp = bias;
  (void)bias2; (void)split;
  float4 bv4[4];
#pragma unroll
  for (int ni = 0; ni < 4; ni++) bv4[ni] = *(const float4*)&bp[col0 + wc * 64 + ni * 16 + kg * 4];
#pragma unroll
  for (int mi = 0; mi < 4; mi++) {
    size_t grow = (size_t)(row0 + wr * 64 + mi * 16 + l15);
#pragma unroll
    for (int ni = 0; ni < 4; ni++) {
      int gcol = col0 + wc * 64 + ni * 16 + kg * 4;
      float v0 = acc[mi][ni][0] + bv4[ni].x;
      float v1 = acc[mi][ni][1] + bv4[ni].y;
      float v2 = acc[mi][ni][2] + bv4[ni].z;
      float v3 = acc[mi][ni][3] + bv4[ni].w;
      if (MODE == 2) {
        float4 fo = {v0, v1, v2, v3};
        *(float4*)&((float*)out)[grow * 1024 + gcol] = fo;
      } else {
        uint2 o;
        asm("v_cvt_pk_bf16_f32 %0, %1, %2" : "=v"(o.x) : "v"(v0), "v"(v1));
        asm("v_cvt_pk_bf16_f32 %0, %1, %2" : "=v"(o.y) : "v"(v2), "v"(v3));
        *(uint2*)&((u16*)out)[grow * 1024 + gcol] = o;
      }
    }
  }
}

// ---------------- fused attention (unchanged, passing) ----------------
__global__ __launch_bounds__(512, 4) void attn_kernel(const u16* __restrict__ q_bf, const u16* __restrict__ k_bf,
                                                      const u16* __restrict__ v_bf, const u16* __restrict__ gk_bf,
                                                      const u16* __restrict__ gv_bf, u16* __restrict__ ao,
                                                      const int* __restrict__ rptr) {
  __shared__ u16 smem[16384];
  const int c = blockIdx.x, h = blockIdx.y, b = blockIdx.z;
  const int tid = threadIdx.x;
  const int lane = tid & 63, wv = tid >> 6;
  const int l31 = lane & 31, half = lane >> 5;
  const int t0 = c * CHUNK_;

  int rr = rptr[0];
  int centert = c * CHUNK_ + CHUNK_ / 2;
  int expected = (int)((float)centert / (float)rr);
  expected = min(max(expected, 0), S_ - 1);
  int ws0 = min(max(expected - W_ / 2, 0), S_ - W_);

  bf16x8 qf[4];
  {
    const u16* qrow = q_bf + ((size_t)(b * T_ + t0 + wv * 32 + l31)) * D_ + h * 64 + half * 8;
#pragma unroll
    for (int s = 0; s < 4; s++) qf[s] = *(const bf16x8*)(qrow + s * 16);
  }

  const int skey = (tid & 255) >> 3, shq = tid & 7;
  const bool isK = tid < 256;

  auto load_tile = [&](int j) -> uint4 {
    const u16* base;
    size_t row;
    if (j < 2) {
      base = isK ? gk_bf : gv_bf;
      row = (size_t)(b * G_ + j * 32 + skey);
    } else {
      base = isK ? k_bf : v_bf;
      row = (size_t)(b * S_ + ws0 + (j - 2) * 32 + skey);
    }
    return *(const uint4*)(base + row * D_ + h * 64 + shq * 8);
  };

  f32x16 oacc[2];
#pragma unroll
  for (int i = 0; i < 2; i++)
#pragma unroll
    for (int r = 0; r < 16; r++) oacc[i][r] = 0.f;
  float mrun = -1e30f, lsum = 0.f;

  uint4 stg = load_tile(0);

  for (int j = 0; j < NT_; j++) {
    const int bsel = j & 1;
    if (isK) {
      *(uint4*)((char*)smem + bsel * 4096 + ((skey * 128 + shq * 16) ^ ((skey & 7) << 4))) = stg;
    } else {
      const u16* pv = (const u16*)&stg;
      char* bp = (char*)smem + 8192 + bsel * 5248 + shq * 656 + skey * 2;  // 656 = 8*80+16 (row skew)
#pragma unroll
      for (int e = 0; e < 8; e++) *(u16*)(bp + e * 80) = pv[e];
    }
    if (j + 1 < NT_) stg = load_tile(j + 1);
    __syncthreads();

    const int kbase = bsel * 4096;
    const int vtb = 8192 + bsel * 5248;

    f32x16 sacc;
#pragma unroll
    for (int r = 0; r < 16; r++) sacc[r] = 0.f;
    __builtin_amdgcn_s_setprio(1);
#pragma unroll
    for (int s = 0; s < 4; s++) {
      int kbx = kbase + ((l31 * 128 + half * 16 + s * 32) ^ ((l31 & 7) << 4));
      bf16x8 kf = *(const bf16x8*)((char*)smem + kbx);
      sacc = __builtin_amdgcn_mfma_f32_32x32x16_bf16(kf, qf[s], sacc, 0, 0, 0);
    }
    __builtin_amdgcn_s_setprio(0);

    float t0m = fmaxf(fmaxf(sacc[0], sacc[1]), sacc[2]);
    float t1m = fmaxf(fmaxf(sacc[3], sacc[4]), sacc[5]);
    float t2m = fmaxf(fmaxf(sacc[6], sacc[7]), sacc[8]);
    float t3m = fmaxf(fmaxf(sacc[9], sacc[10]), sacc[11]);
    float t4m = fmaxf(fmaxf(sacc[12], sacc[13]), sacc[14]);
    float tmax = fmaxf(fmaxf(fmaxf(t0m, t1m), fmaxf(t2m, t3m)), fmaxf(t4m, sacc[15]));
    tmax = fmaxf(tmax, __shfl_xor(tmax, 32));
    if (__any(tmax > mrun + 8.f)) {
      float mnew = fmaxf(mrun, tmax);
      float fac = __builtin_amdgcn_exp2f(mrun - mnew);
      mrun = mnew;
      lsum *= fac;
#pragma unroll
      for (int i = 0; i < 2; i++)
#pragma unroll
        for (int r = 0; r < 16; r++) oacc[i][r] *= fac;
    }
    float p[16];
#pragma unroll
    for (int r = 0; r < 16; r++) p[r] = __builtin_amdgcn_exp2f(sacc[r] - mrun);
    float s0s = (p[0] + p[1]) + (p[2] + p[3]);
    float s1s = (p[4] + p[5]) + (p[6] + p[7]);
    float s2s = (p[8] + p[9]) + (p[10] + p[11]);
    float s3s = (p[12] + p[13]) + (p[14] + p[15]);
    float tsum = (s0s + s1s) + (s2s + s3s);
    tsum += __shfl_xor(tsum, 32);
    lsum += tsum;

    u32 xs[8], px[8];
#pragma unroll
    for (int i = 0; i < 8; i++)
      asm("v_cvt_pk_bf16_f32 %0, %1, %2" : "=v"(xs[i]) : "v"(p[2 * i]), "v"(p[2 * i + 1]));
#pragma unroll
    for (int i = 0; i < 8; i++) px[i] = (u32)__shfl_xor((int)xs[i], 32);
    u32 Bk[2][4];
    Bk[0][0] = half ? px[2] : xs[0];
    Bk[0][1] = half ? px[3] : xs[1];
    Bk[0][2] = half ? xs[2] : px[0];
    Bk[0][3] = half ? xs[3] : px[1];
    Bk[1][0] = half ? px[6] : xs[4];
    Bk[1][1] = half ? px[7] : xs[5];
    Bk[1][2] = half ? xs[6] : px[4];
    Bk[1][3] = half ? xs[7] : px[5];

    int vro = vtb + l31 * 80 + ((l31 >> 3) << 4) + half * 16;
    __builtin_amdgcn_s_setprio(1);
#pragma unroll
    for (int hdf = 0; hdf < 2; hdf++) {
#pragma unroll
      for (int ks = 0; ks < 2; ks++) {
        bf16x8 vf = *(const bf16x8*)((const char*)smem + vro + hdf * 2624 + ks * 32);  // 2624 = 32*80+64
        uint4 u4;
        u4.x = Bk[ks][0]; u4.y = Bk[ks][1]; u4.z = Bk[ks][2]; u4.w = Bk[ks][3];
        bf16x8 pb = __builtin_bit_cast(bf16x8, u4);
        oacc[hdf] = __builtin_amdgcn_mfma_f32_32x32x16_bf16(vf, pb, oacc[hdf], 0, 0, 0);
      }
    }
    __builtin_amdgcn_s_setprio(0);
  }

  __syncthreads();
  float inv = 1.f / lsum;
#pragma unroll
  for (int hdf = 0; hdf < 2; hdf++) {
#pragma unroll
    for (int a = 0; a < 4; a++) {
      float f0 = oacc[hdf][4 * a] * inv, f1 = oacc[hdf][4 * a + 1] * inv;
      float f2 = oacc[hdf][4 * a + 2] * inv, f3 = oacc[hdf][4 * a + 3] * inv;
      uint2 o;
      asm("v_cvt_pk_bf16_f32 %0, %1, %2" : "=v"(o.x) : "v"(f0), "v"(f1));
      asm("v_cvt_pk_bf16_f32 %0, %1, %2" : "=v"(o.y) : "v"(f2), "v"(f3));
      int off = wv * 4096 + l31 * 128 + ((16 * a + 8 * half + 64 * hdf) ^ ((l31 & 7) << 4));
      *(uint2*)((char*)smem + off) = o;
    }
  }
  __syncthreads();
#pragma unroll
  for (int it = 0; it < 4; it++) {
    int byteo = (tid + it * 512) * 16;
    int row = byteo >> 7;
    int colb = byteo & 127;
    uint4 vv = *(const uint4*)((const char*)smem + row * 128 + (colb ^ ((row & 7) << 4)));
    *(uint4*)(ao + ((size_t)(b * T_ + t0 + row)) * D_ + h * 64 + (colb >> 1)) = vv;
  }
}

extern "C" void kernel_launch(void* const* d_in, const int* in_sizes, int n_in,
                              void* d_out, int out_size, void* d_ws, size_t ws_size,
                              hipStream_t stream) {
  (void)in_sizes; (void)n_in; (void)out_size; (void)ws_size;
  const float* query = (const float*)d_in[0];
  const float* enc = (const float*)d_in[1];
  const float* glob = (const float*)d_in[2];
  const float* qw = (const float*)d_in[3];
  const float* qb = (const float*)d_in[4];
  const float* kw = (const float*)d_in[5];
  const float* kb = (const float*)d_in[6];
  const float* vw = (const float*)d_in[7];
  const float* vb = (const float*)d_in[8];
  const float* gkw = (const float*)d_in[9];
  const float* gkb = (const float*)d_in[10];
  const float* gvw = (const float*)d_in[11];
  const float* gvb = (const float*)d_in[12];
  const float* ow = (const float*)d_in[13];
  const float* ob = (const float*)d_in[14];
  const int* rp = (const int*)d_in[15];

  const size_t NQ = (size_t)B_ * T_ * D_;   // 8388608
  const size_t NG = (size_t)B_ * G_ * D_;   // 131072
  const size_t NW = (size_t)D_ * D_;        // 1048576

  u16* ws = (u16*)d_ws;
  u16* qx = ws;                // bf16 query
  u16* ex = qx + NQ;           // bf16 encoder_out
  u16* gx = ex + NQ;           // bf16 global_tokens
  u16* wgt = gx + NG;          // 6 weights bf16 (qw,kw,vw,gkw,gvw,ow) — contiguous
  u16* q_bf = wgt + 6 * NW;    // projected q (pre-scaled by 0.125*log2e)
  u16* k_bf = q_bf + NQ;
  u16* v_bf = k_bf + NQ;       // contiguous after k_bf (fused K|V)
  u16* gk_bf = v_bf + NQ;
  u16* gv_bf = gk_bf + NG;     // contiguous after gk_bf (fused GK|GV)
  u16* ao = gv_bf + NG;        // attention output bf16 [B*T, D]

  // one fused conversion dispatch: 8192+8192+128+6*1024 = 22656 blocks
  cvt_all_kernel<<<22656, 256, 0, stream>>>(query, enc, glob, qw, kw, vw, gkw, gvw, ow, ws);

  // merged Q + K|V + GK|GV projection: 512 + 256 + 16 = 784 blocks (2 resident/CU)
  proj_kernel<<<784, 256, 0, stream>>>(ex, qx, gx, wgt, qb, kb, vb, gkb, gvb, q_bf, k_bf, gk_bf);

  attn_kernel<<<dim3(NC_, H_, B_), 512, 0, stream>>>(q_bf, k_bf, v_bf, gk_bf, gv_bf, ao, rp);

  gemm_kernel<2><<<dim3(64, 8), 256, 0, stream>>>(ao, wgt + 5 * NW, ob, ob, 0, d_out);
}